// Round 1
// baseline (71.775 us; speedup 1.0000x reference)
//
#include <hip/hip_runtime.h>

// LIF spike scan: x[B=256, C=1024, T=128] f32 -> spikes same shape.
// Recurrence per (b,c) row over t:
//   mem = mem*TAU + x_t; spike = (mem - THRESH > 0); mem -= spike*THRESH
// TAU = 0.5, THRESH = 0.5.
// One thread per row (T is contiguous), float4 vectorized.

#define TAU 0.5f
#define THRESH 0.5f

__global__ __launch_bounds__(256) void lif_kernel(const float* __restrict__ x,
                                                  float* __restrict__ out) {
    const int row = blockIdx.x * blockDim.x + threadIdx.x;  // 0 .. 262143
    const long long base = (long long)row * 128;
    const float4* __restrict__ xin = reinterpret_cast<const float4*>(x + base);
    float4* __restrict__ o = reinterpret_cast<float4*>(out + base);

    float mem = 0.0f;
#pragma unroll
    for (int j = 0; j < 32; ++j) {
        float4 v = xin[j];
        float4 s;

        mem = mem * TAU + v.x;
        s.x = (mem > THRESH) ? 1.0f : 0.0f;
        mem -= s.x * THRESH;

        mem = mem * TAU + v.y;
        s.y = (mem > THRESH) ? 1.0f : 0.0f;
        mem -= s.y * THRESH;

        mem = mem * TAU + v.z;
        s.z = (mem > THRESH) ? 1.0f : 0.0f;
        mem -= s.z * THRESH;

        mem = mem * TAU + v.w;
        s.w = (mem > THRESH) ? 1.0f : 0.0f;
        mem -= s.w * THRESH;

        o[j] = s;
    }
}

extern "C" void kernel_launch(void* const* d_in, const int* in_sizes, int n_in,
                              void* d_out, int out_size, void* d_ws, size_t ws_size,
                              hipStream_t stream) {
    const float* x = (const float*)d_in[0];
    float* out = (float*)d_out;
    // rows = B*C = out_size / T
    const int rows = out_size / 128;  // 262144
    const int block = 256;
    const int grid = rows / block;    // 1024
    lif_kernel<<<grid, block, 0, stream>>>(x, out);
}